// Round 1
// baseline (1977.424 us; speedup 1.0000x reference)
//
#include <hip/hip_runtime.h>
#include <hip/hip_fp16.h>

#define BATCH 4
#define NSEQ 2048
#define DMODEL 512
#define NHEAD 8
#define HDIM 64
#define LSEL 32

// ---------------------------------------------------------------------------
// proj: C = A[M,512] @ W[512,512] -> head-split [B,H,N,64].  z picks q/k/v.
// 64x64 tile, BK=16, 256 threads, 4x4 micro-tile per thread.
// ---------------------------------------------------------------------------
__global__ __launch_bounds__(256) void proj_kernel(
    const float* __restrict__ qin, const float* __restrict__ kin, const float* __restrict__ vin,
    const float* __restrict__ Wq, const float* __restrict__ Wk, const float* __restrict__ Wv,
    float* __restrict__ qh, float* __restrict__ kh, float* __restrict__ vh)
{
    const int z = blockIdx.z;
    const float* A = (z == 0) ? qin : (z == 1) ? kin : vin;
    const float* W = (z == 0) ? Wq : (z == 1) ? Wk : Wv;
    float* Out = (z == 0) ? qh : (z == 1) ? kh : vh;

    __shared__ __align__(16) float As[16][68];   // As[k][m]
    __shared__ __align__(16) float Bs[16][68];   // Bs[k][n]

    const int tid = threadIdx.x;
    const int tx = tid & 15;        // col group
    const int ty = tid >> 4;        // row group
    const int bm = blockIdx.y * 64;
    const int bn = blockIdx.x * 64;

    // staging indices
    const int sa_m = tid >> 2;            // 0..63
    const int sa_kq = (tid & 3) * 4;      // 0,4,8,12
    const int sb_k = tid >> 4;            // 0..15
    const int sb_n = (tid & 15) * 4;      // 0..60

    float acc[4][4] = {};

    for (int k0 = 0; k0 < DMODEL; k0 += 16) {
        __syncthreads();
        {
            float4 a4 = *(const float4*)(A + (size_t)(bm + sa_m) * DMODEL + k0 + sa_kq);
            As[sa_kq + 0][sa_m] = a4.x;
            As[sa_kq + 1][sa_m] = a4.y;
            As[sa_kq + 2][sa_m] = a4.z;
            As[sa_kq + 3][sa_m] = a4.w;
        }
        {
            float4 b4 = *(const float4*)(W + (size_t)(k0 + sb_k) * DMODEL + bn + sb_n);
            *(float4*)&Bs[sb_k][sb_n] = b4;
        }
        __syncthreads();
#pragma unroll
        for (int kk = 0; kk < 16; ++kk) {
            float4 a4 = *(const float4*)&As[kk][ty * 4];
            float4 b4 = *(const float4*)&Bs[kk][tx * 4];
            float av[4] = {a4.x, a4.y, a4.z, a4.w};
            float bv[4] = {b4.x, b4.y, b4.z, b4.w};
#pragma unroll
            for (int i = 0; i < 4; ++i)
#pragma unroll
                for (int j = 0; j < 4; ++j)
                    acc[i][j] += av[i] * bv[j];
        }
    }

    const int h = bn >> 6;   // BN=64-aligned -> single head per block column
#pragma unroll
    for (int i = 0; i < 4; ++i) {
        int mg = bm + ty * 4 + i;
        int b = mg >> 11;        // / NSEQ
        int n = mg & (NSEQ - 1);
        float4 o = {acc[i][0], acc[i][1], acc[i][2], acc[i][3]};
        *(float4*)(Out + ((size_t)(b * NHEAD + h) * NSEQ + n) * HDIM + tx * 4) = o;
    }
}

// ---------------------------------------------------------------------------
// attn: per (b,h), 8 q-rows per block (1 per wave). Scores in registers
// (32/lane), exact 32nd-largest via bit-pattern binary search, PV cooperative.
// ---------------------------------------------------------------------------
__global__ __launch_bounds__(512) void attn_kernel(
    const float* __restrict__ qh, const float* __restrict__ kh, const float* __restrict__ vh,
    float* __restrict__ ao)
{
    __shared__ __align__(16) float tile[64][68];     // K or V tile (17.4 KB)
    __shared__ __align__(16) __half wbuf[8][NSEQ];   // normalized weights (32 KB)

    const int tid = threadIdx.x;
    const int wave = tid >> 6;
    const int lane = tid & 63;
    const int bh = blockIdx.y;                 // b*NHEAD + h
    const int row = blockIdx.x * 8 + wave;

    const float* Kbase = kh + (size_t)bh * NSEQ * HDIM;
    const float* Vbase = vh + (size_t)bh * NSEQ * HDIM;
    const float* Qrow  = qh + ((size_t)bh * NSEQ + row) * HDIM;

    // q row in registers, pre-scaled by 1/sqrt(DK)=0.125
    float4 q[16];
#pragma unroll
    for (int j = 0; j < 16; ++j) {
        float4 t4 = ((const float4*)Qrow)[j];
        q[j].x = t4.x * 0.125f; q[j].y = t4.y * 0.125f;
        q[j].z = t4.z * 0.125f; q[j].w = t4.w * 0.125f;
    }

    float s[32];

    const int st_key = tid >> 4;          // 0..31 (and +32)
    const int st_d4 = (tid & 15) * 4;

    // -------- scores: S[row, :] over 32 tiles of 64 keys --------
    for (int t = 0; t < 32; ++t) {
        __syncthreads();
        {
            const float* src = Kbase + (size_t)(t * 64) * HDIM;
            *(float4*)&tile[st_key][st_d4]      = *(const float4*)(src + (size_t)st_key * HDIM + st_d4);
            *(float4*)&tile[st_key + 32][st_d4] = *(const float4*)(src + (size_t)(st_key + 32) * HDIM + st_d4);
        }
        __syncthreads();
        float a = 0.f;
#pragma unroll
        for (int j = 0; j < 16; ++j) {
            float4 k4 = *(const float4*)&tile[lane][j * 4];
            a += q[j].x * k4.x + q[j].y * k4.y + q[j].z * k4.z + q[j].w * k4.w;
        }
        s[t] = a;
    }

    // -------- row max + unnormalized exp (softmax denom cancels in AWG) -----
    float m = s[0];
#pragma unroll
    for (int t = 1; t < 32; ++t) m = fmaxf(m, s[t]);
#pragma unroll
    for (int off = 32; off >= 1; off >>= 1) m = fmaxf(m, __shfl_xor(m, off));

#pragma unroll
    for (int t = 0; t < 32; ++t) s[t] = exp2f((s[t] - m) * 1.4426950408889634f);

    // -------- exact 32nd-largest of the 2048 e-values (bit binary search) ---
    unsigned lo = 0u, hi = 0x3F800000u;   // e in (0, 1]
    while (lo < hi) {
        unsigned mid = (lo + hi + 1) >> 1;
        float mf = __uint_as_float(mid);
        int cnt = 0;
#pragma unroll
        for (int t = 0; t < 32; ++t) cnt += (s[t] >= mf) ? 1 : 0;
#pragma unroll
        for (int off = 32; off >= 1; off >>= 1) cnt += __shfl_xor(cnt, off);
        if (cnt >= LSEL) lo = mid; else hi = mid - 1;
    }
    const float thr = __uint_as_float(lo);

    // -------- mask + renormalize, stash weights as fp16 in LDS --------------
    float wsum = 0.f;
#pragma unroll
    for (int t = 0; t < 32; ++t) {
        float w = (s[t] >= thr) ? s[t] : 0.f;
        s[t] = w;
        wsum += w;
    }
#pragma unroll
    for (int off = 32; off >= 1; off >>= 1) wsum += __shfl_xor(wsum, off);
    const float winv = 1.f / wsum;

#pragma unroll
    for (int t = 0; t < 32; ++t)
        wbuf[wave][t * 64 + lane] = __float2half(s[t] * winv);

    // -------- PV: out[row][d] = sum_k w[k] * V[k][d] ------------------------
    const int ko = lane >> 4;     // key offset 0..3
    const int dg = lane & 15;     // dim group (4 dims)
    float4 acc = {0.f, 0.f, 0.f, 0.f};

    for (int t = 0; t < 32; ++t) {
        __syncthreads();     // prev tile reads done (also orders wbuf w->r)
        {
            const float* src = Vbase + (size_t)(t * 64) * HDIM;
            *(float4*)&tile[st_key][st_d4]      = *(const float4*)(src + (size_t)st_key * HDIM + st_d4);
            *(float4*)&tile[st_key + 32][st_d4] = *(const float4*)(src + (size_t)(st_key + 32) * HDIM + st_d4);
        }
        __syncthreads();
#pragma unroll
        for (int i = 0; i < 16; ++i) {
            int k = i * 4 + ko;
            float w = __half2float(wbuf[wave][t * 64 + k]);
            float4 v4 = *(const float4*)&tile[k][dg * 4];
            acc.x += w * v4.x; acc.y += w * v4.y;
            acc.z += w * v4.z; acc.w += w * v4.w;
        }
    }

    acc.x += __shfl_xor(acc.x, 16); acc.y += __shfl_xor(acc.y, 16);
    acc.z += __shfl_xor(acc.z, 16); acc.w += __shfl_xor(acc.w, 16);
    acc.x += __shfl_xor(acc.x, 32); acc.y += __shfl_xor(acc.y, 32);
    acc.z += __shfl_xor(acc.z, 32); acc.w += __shfl_xor(acc.w, 32);

    if (ko == 0) {
        int b = bh >> 3, h = bh & 7;
        *(float4*)(ao + ((size_t)(b * NSEQ + row) * DMODEL) + h * HDIM + dg * 4) = acc;
    }
}

// ---------------------------------------------------------------------------
// fc + residual + LayerNorm: 8 rows/block, 256 threads; x transposed in LDS.
// ---------------------------------------------------------------------------
__global__ __launch_bounds__(256) void fc_ln_kernel(
    const float* __restrict__ ao, const float* __restrict__ Wfc,
    const float* __restrict__ resid, const float* __restrict__ gamma,
    const float* __restrict__ beta, float* __restrict__ out)
{
    __shared__ __align__(16) float xs[DMODEL][12];       // xs[k][r] (24 KB)
    __shared__ __align__(16) float os[8][DMODEL + 4];    // LN staging (16.1 KB)

    const int tid = threadIdx.x;
    const int m0 = blockIdx.x * 8;

    // stage x transposed
#pragma unroll
    for (int it = 0; it < 4; ++it) {
        int f = tid + 256 * it;
        int r = f & 7;
        int kq = (f >> 3) * 4;
        float4 x4 = *(const float4*)(ao + (size_t)(m0 + r) * DMODEL + kq);
        xs[kq + 0][r] = x4.x;
        xs[kq + 1][r] = x4.y;
        xs[kq + 2][r] = x4.z;
        xs[kq + 3][r] = x4.w;
    }
    __syncthreads();

    const int j0 = tid;
    const int j1 = tid + 256;
    float acc0[8] = {}, acc1[8] = {};
#pragma unroll 4
    for (int k = 0; k < DMODEL; ++k) {
        float w0 = Wfc[(size_t)k * DMODEL + j0];
        float w1 = Wfc[(size_t)k * DMODEL + j1];
        float4 xa = *(const float4*)&xs[k][0];
        float4 xb = *(const float4*)&xs[k][4];
        acc0[0] += xa.x * w0; acc0[1] += xa.y * w0; acc0[2] += xa.z * w0; acc0[3] += xa.w * w0;
        acc0[4] += xb.x * w0; acc0[5] += xb.y * w0; acc0[6] += xb.z * w0; acc0[7] += xb.w * w0;
        acc1[0] += xa.x * w1; acc1[1] += xa.y * w1; acc1[2] += xa.z * w1; acc1[3] += xa.w * w1;
        acc1[4] += xb.x * w1; acc1[5] += xb.y * w1; acc1[6] += xb.z * w1; acc1[7] += xb.w * w1;
    }

    // residual add, stash rows for LN
#pragma unroll
    for (int r = 0; r < 8; ++r) {
        os[r][j0] = acc0[r] + resid[(size_t)(m0 + r) * DMODEL + j0];
        os[r][j1] = acc1[r] + resid[(size_t)(m0 + r) * DMODEL + j1];
    }
    __syncthreads();

    // LayerNorm: wave w handles rows 2w, 2w+1; each lane owns 8 columns
    const int wv = tid >> 6, ln = tid & 63;
#pragma unroll
    for (int rr = wv * 2; rr < wv * 2 + 2; ++rr) {
        float4 va = *(const float4*)&os[rr][ln * 8];
        float4 vb = *(const float4*)&os[rr][ln * 8 + 4];
        float sum = va.x + va.y + va.z + va.w + vb.x + vb.y + vb.z + vb.w;
        float sq = va.x * va.x + va.y * va.y + va.z * va.z + va.w * va.w
                 + vb.x * vb.x + vb.y * vb.y + vb.z * vb.z + vb.w * vb.w;
#pragma unroll
        for (int off = 32; off >= 1; off >>= 1) {
            sum += __shfl_xor(sum, off);
            sq += __shfl_xor(sq, off);
        }
        float mean = sum * (1.f / 512.f);
        float var = sq * (1.f / 512.f) - mean * mean;
        float rstd = rsqrtf(var + 1e-6f);

        float4 ga = *(const float4*)(gamma + ln * 8);
        float4 gb = *(const float4*)(gamma + ln * 8 + 4);
        float4 ba = *(const float4*)(beta + ln * 8);
        float4 bb = *(const float4*)(beta + ln * 8 + 4);

        float4 oa, ob;
        oa.x = (va.x - mean) * rstd * ga.x + ba.x;
        oa.y = (va.y - mean) * rstd * ga.y + ba.y;
        oa.z = (va.z - mean) * rstd * ga.z + ba.z;
        oa.w = (va.w - mean) * rstd * ga.w + ba.w;
        ob.x = (vb.x - mean) * rstd * gb.x + bb.x;
        ob.y = (vb.y - mean) * rstd * gb.y + bb.y;
        ob.z = (vb.z - mean) * rstd * gb.z + bb.z;
        ob.w = (vb.w - mean) * rstd * gb.w + bb.w;

        *(float4*)(out + (size_t)(m0 + rr) * DMODEL + ln * 8) = oa;
        *(float4*)(out + (size_t)(m0 + rr) * DMODEL + ln * 8 + 4) = ob;
    }
}

extern "C" void kernel_launch(void* const* d_in, const int* in_sizes, int n_in,
                              void* d_out, int out_size, void* d_ws, size_t ws_size,
                              hipStream_t stream)
{
    (void)in_sizes; (void)n_in; (void)out_size; (void)ws_size;

    const float* q   = (const float*)d_in[0];
    const float* k   = (const float*)d_in[1];
    const float* v   = (const float*)d_in[2];
    const float* Wq  = (const float*)d_in[3];
    const float* Wk  = (const float*)d_in[4];
    const float* Wv  = (const float*)d_in[5];
    const float* Wfc = (const float*)d_in[6];
    const float* g   = (const float*)d_in[7];
    const float* b   = (const float*)d_in[8];
    float* out = (float*)d_out;

    float* ws = (float*)d_ws;
    const size_t per = (size_t)BATCH * NSEQ * DMODEL;   // 4,194,304 floats
    float* qh = ws;
    float* kh = ws + per;
    float* vh = ws + 2 * per;
    float* ao = ws + 3 * per;

    dim3 pgrid(DMODEL / 64, (BATCH * NSEQ) / 64, 3);    // 8 x 128 x 3
    proj_kernel<<<pgrid, 256, 0, stream>>>(q, k, v, Wq, Wk, Wv, qh, kh, vh);

    dim3 agrid(NSEQ / 8, BATCH * NHEAD);                // 256 x 32
    attn_kernel<<<agrid, 512, 0, stream>>>(qh, kh, vh, ao);

    fc_ln_kernel<<<(BATCH * NSEQ) / 8, 256, 0, stream>>>(ao, Wfc, q, g, b, out);
}

// Round 2
// 616.408 us; speedup vs baseline: 3.2080x; 3.2080x over previous
//
#include <hip/hip_runtime.h>
#include <hip/hip_fp16.h>
#include <hip/hip_bf16.h>

#define BATCH 4
#define NSEQ 2048
#define DMODEL 512
#define NHEAD 8
#define HDIM 64
#define LSEL 32
#define SROW 2056     // 2048 + 8 halfs pad (16B) per score row
#define MAXL 96       // selected-key list capacity (>=32 + tie headroom)

typedef __attribute__((ext_vector_type(8))) short bf16x8s;
typedef __attribute__((ext_vector_type(4))) float f32x4;

__device__ inline ushort f2bf(float x) {
    __hip_bfloat16 h = __float2bfloat16(x);
    return *reinterpret_cast<ushort*>(&h);
}

// ---------------------------------------------------------------------------
// proj: C = A[M,512] @ W[512,512].  z=0(Q),1(K): bf16 out [B,H,N,64];
// z=2(V): fp32 out [B,H,N,64].  64x64 tile, BK=16, 256 thr, 4x4 micro-tile.
// ---------------------------------------------------------------------------
__global__ __launch_bounds__(256) void proj_kernel(
    const float* __restrict__ qin, const float* __restrict__ kin, const float* __restrict__ vin,
    const float* __restrict__ Wq, const float* __restrict__ Wk, const float* __restrict__ Wv,
    ushort* __restrict__ qhb, ushort* __restrict__ khb, float* __restrict__ vh)
{
    const int z = blockIdx.z;
    const float* A = (z == 0) ? qin : (z == 1) ? kin : vin;
    const float* W = (z == 0) ? Wq : (z == 1) ? Wk : Wv;

    __shared__ __align__(16) float As[16][68];   // As[k][m]
    __shared__ __align__(16) float Bs[16][68];   // Bs[k][n]

    const int tid = threadIdx.x;
    const int tx = tid & 15;
    const int ty = tid >> 4;
    const int bm = blockIdx.y * 64;
    const int bn = blockIdx.x * 64;

    const int sa_m = tid >> 2;
    const int sa_kq = (tid & 3) * 4;
    const int sb_k = tid >> 4;
    const int sb_n = (tid & 15) * 4;

    float acc[4][4] = {};

    for (int k0 = 0; k0 < DMODEL; k0 += 16) {
        __syncthreads();
        {
            float4 a4 = *(const float4*)(A + (size_t)(bm + sa_m) * DMODEL + k0 + sa_kq);
            As[sa_kq + 0][sa_m] = a4.x;
            As[sa_kq + 1][sa_m] = a4.y;
            As[sa_kq + 2][sa_m] = a4.z;
            As[sa_kq + 3][sa_m] = a4.w;
        }
        {
            float4 b4 = *(const float4*)(W + (size_t)(k0 + sb_k) * DMODEL + bn + sb_n);
            *(float4*)&Bs[sb_k][sb_n] = b4;
        }
        __syncthreads();
#pragma unroll
        for (int kk = 0; kk < 16; ++kk) {
            float4 a4 = *(const float4*)&As[kk][ty * 4];
            float4 b4 = *(const float4*)&Bs[kk][tx * 4];
            float av[4] = {a4.x, a4.y, a4.z, a4.w};
            float bv[4] = {b4.x, b4.y, b4.z, b4.w};
#pragma unroll
            for (int i = 0; i < 4; ++i)
#pragma unroll
                for (int j = 0; j < 4; ++j)
                    acc[i][j] += av[i] * bv[j];
        }
    }

    const int h = bn >> 6;
#pragma unroll
    for (int i = 0; i < 4; ++i) {
        int mg = bm + ty * 4 + i;
        int b = mg >> 11;
        int n = mg & (NSEQ - 1);
        size_t off = ((size_t)(b * NHEAD + h) * NSEQ + n) * HDIM + tx * 4;
        if (z == 0) {
            ushort4 o = {f2bf(acc[i][0]), f2bf(acc[i][1]), f2bf(acc[i][2]), f2bf(acc[i][3])};
            *(ushort4*)(qhb + off) = o;
        } else if (z == 1) {
            ushort4 o = {f2bf(acc[i][0]), f2bf(acc[i][1]), f2bf(acc[i][2]), f2bf(acc[i][3])};
            *(ushort4*)(khb + off) = o;
        } else {
            float4 o = {acc[i][0], acc[i][1], acc[i][2], acc[i][3]};
            *(float4*)(vh + off) = o;
        }
    }
}

// ---------------------------------------------------------------------------
// attn v2: per block = (b,h) x 16 q-rows, 8 waves.
// Phase 1: QK^T via mfma_16x16x32_bf16 (swapped: D[key][qrow]); wave w owns
//          keys [w*256, w*256+256); scores (x0.125) -> fp16 LDS S[16][2056].
// Phase 2: per q-row (2 per wave): coalesced b128 score load (32/lane),
//          exact 32nd-largest via 16-iter binary search on sortable u16,
//          ballot-prefix compaction (deterministic), sparse PV over fp32 V.
// ---------------------------------------------------------------------------
__global__ __launch_bounds__(512, 4) void attn_kernel(
    const ushort* __restrict__ qh, const ushort* __restrict__ kh,
    const float* __restrict__ vh, float* __restrict__ ao)
{
    __shared__ __align__(16) __half Sbuf[16 * SROW];   // 65792 B
    __shared__ ushort lidx[16][MAXL];
    __shared__ float  lw[16][MAXL];

    const int tid  = threadIdx.x;
    const int wave = tid >> 6;
    const int lane = tid & 63;
    const int bh   = blockIdx.y;
    const int q0   = blockIdx.x * 16;
    const int lr   = lane & 15;     // row (A) / col (B,D) within 16
    const int lg   = lane >> 4;     // k-group

    const ushort* Qb = qh + ((size_t)bh * NSEQ + q0) * HDIM;
    const ushort* Kb = kh + (size_t)bh * NSEQ * HDIM;

    // Q fragments (B operand): col=lane&15 (q-row), k=(lane>>4)*8 + 0..7 (+32 for step 2)
    bf16x8s qf0 = *(const bf16x8s*)(Qb + lr * HDIM + lg * 8);
    bf16x8s qf1 = *(const bf16x8s*)(Qb + lr * HDIM + 32 + lg * 8);

    // -------- Phase 1: scores --------
    for (int t = 0; t < 16; ++t) {
        const int k0 = wave * 256 + t * 16;
        const ushort* Kt = Kb + (size_t)k0 * HDIM;
        bf16x8s a0 = *(const bf16x8s*)(Kt + lr * HDIM + lg * 8);
        bf16x8s a1 = *(const bf16x8s*)(Kt + lr * HDIM + 32 + lg * 8);
        f32x4 acc = {0.f, 0.f, 0.f, 0.f};
        acc = __builtin_amdgcn_mfma_f32_16x16x32_bf16(a0, qf0, acc, 0, 0, 0);
        acc = __builtin_amdgcn_mfma_f32_16x16x32_bf16(a1, qf1, acc, 0, 0, 0);
        // D: col=lane&15 = q-row, row=(lane>>4)*4+reg = key offset
        __half2* dst = reinterpret_cast<__half2*>(&Sbuf[lr * SROW + k0 + lg * 4]);
        dst[0] = __halves2half2(__float2half(acc[0] * 0.125f), __float2half(acc[1] * 0.125f));
        dst[1] = __halves2half2(__float2half(acc[2] * 0.125f), __float2half(acc[3] * 0.125f));
    }
    __syncthreads();

    // -------- Phase 2: selection + sparse PV --------
    const float* Vb = vh + (size_t)bh * NSEQ * HDIM;
    const int b = bh >> 3, hh = bh & 7;

    for (int rr = 0; rr < 2; ++rr) {
        const int qr = wave * 2 + rr;
        const char* Srow = reinterpret_cast<const char*>(&Sbuf[qr * SROW]);

        // load 32 scores/lane, coalesced b128; map to sortable uint16
        int u[32];
#pragma unroll
        for (int it = 0; it < 4; ++it) {
            uint4 raw = *reinterpret_cast<const uint4*>(Srow + it * 1024 + lane * 16);
            unsigned wds[4] = {raw.x, raw.y, raw.z, raw.w};
#pragma unroll
            for (int e = 0; e < 4; ++e) {
                unsigned wd = wds[e];
                unsigned h0 = wd & 0xFFFFu, h1 = wd >> 16;
                u[it * 8 + e * 2 + 0] = (int)((h0 & 0x8000u) ? (0xFFFFu ^ h0) : (h0 | 0x8000u));
                u[it * 8 + e * 2 + 1] = (int)((h1 & 0x8000u) ? (0xFFFFu ^ h1) : (h1 | 0x8000u));
            }
        }

        // row max (for exp stability)
        int mx = u[0];
#pragma unroll
        for (int j = 1; j < 32; ++j) mx = max(mx, u[j]);
#pragma unroll
        for (int off = 32; off >= 1; off >>= 1) mx = max(mx, __shfl_xor(mx, off));
        ushort mh = (mx & 0x8000) ? (ushort)(mx ^ 0x8000) : (ushort)(~mx & 0xFFFF);
        float M;
        { __half t; *reinterpret_cast<ushort*>(&t) = mh; M = __half2float(t); }

        // exact 32nd-largest on stored fp16 values (16-bit binary search)
        int lo = 0, hi = 0xFFFF;
        while (lo < hi) {
            int mid = (lo + hi + 1) >> 1;
            int c = 0;
#pragma unroll
            for (int j = 0; j < 32; ++j) c += (u[j] >= mid) ? 1 : 0;
#pragma unroll
            for (int off = 32; off >= 1; off >>= 1) c += __shfl_xor(c, off);
            if (c >= LSEL) lo = mid; else hi = mid - 1;
        }

        // deterministic compaction of selected keys + exp weights
        int base = 0;
        float mysum = 0.f;
#pragma unroll
        for (int j = 0; j < 32; ++j) {
            bool p = (u[j] >= lo);
            unsigned long long mb = __ballot(p);
            if (p) {
                int pos = base + __popcll(mb & ((1ULL << lane) - 1ULL));
                if (pos < MAXL) {
                    ushort hb = (u[j] & 0x8000) ? (ushort)(u[j] ^ 0x8000) : (ushort)(~u[j] & 0xFFFF);
                    __half th; *reinterpret_cast<ushort*>(&th) = hb;
                    float s = __half2float(th);
                    float w = exp2f((s - M) * 1.4426950408889634f);
                    lidx[qr][pos] = (ushort)((j >> 3) * 512 + lane * 8 + (j & 7));
                    lw[qr][pos] = w;
                    mysum += w;
                }
            }
            base += __popcll(mb);
        }
#pragma unroll
        for (int off = 32; off >= 1; off >>= 1) mysum += __shfl_xor(mysum, off);
        const int nk = (base < MAXL) ? base : MAXL;

        asm volatile("s_waitcnt lgkmcnt(0)" ::: "memory");

        // sparse PV: lane = output dim; gather selected V rows (fp32, L2-hot)
        float o = 0.f;
        int j2 = 0;
        for (; j2 + 4 <= nk; j2 += 4) {
            int i0 = lidx[qr][j2 + 0]; float w0 = lw[qr][j2 + 0];
            int i1 = lidx[qr][j2 + 1]; float w1 = lw[qr][j2 + 1];
            int i2 = lidx[qr][j2 + 2]; float w2 = lw[qr][j2 + 2];
            int i3 = lidx[qr][j2 + 3]; float w3 = lw[qr][j2 + 3];
            float v0 = Vb[(size_t)i0 * HDIM + lane];
            float v1 = Vb[(size_t)i1 * HDIM + lane];
            float v2 = Vb[(size_t)i2 * HDIM + lane];
            float v3 = Vb[(size_t)i3 * HDIM + lane];
            o += w0 * v0; o += w1 * v1; o += w2 * v2; o += w3 * v3;
        }
        for (; j2 < nk; ++j2) {
            int i0 = lidx[qr][j2]; float w0 = lw[qr][j2];
            o += w0 * Vb[(size_t)i0 * HDIM + lane];
        }

        ao[((size_t)(b * NSEQ) + q0 + qr) * DMODEL + hh * HDIM + lane] = o / mysum;
    }
}

// ---------------------------------------------------------------------------
// fc + residual + LayerNorm: 8 rows/block, 256 threads; x transposed in LDS.
// ---------------------------------------------------------------------------
__global__ __launch_bounds__(256) void fc_ln_kernel(
    const float* __restrict__ ao, const float* __restrict__ Wfc,
    const float* __restrict__ resid, const float* __restrict__ gamma,
    const float* __restrict__ beta, float* __restrict__ out)
{
    __shared__ __align__(16) float xs[DMODEL][12];
    __shared__ __align__(16) float os[8][DMODEL + 4];

    const int tid = threadIdx.x;
    const int m0 = blockIdx.x * 8;

#pragma unroll
    for (int it = 0; it < 4; ++it) {
        int f = tid + 256 * it;
        int r = f & 7;
        int kq = (f >> 3) * 4;
        float4 x4 = *(const float4*)(ao + (size_t)(m0 + r) * DMODEL + kq);
        xs[kq + 0][r] = x4.x;
        xs[kq + 1][r] = x4.y;
        xs[kq + 2][r] = x4.z;
        xs[kq + 3][r] = x4.w;
    }
    __syncthreads();

    const int j0 = tid;
    const int j1 = tid + 256;
    float acc0[8] = {}, acc1[8] = {};
#pragma unroll 4
    for (int k = 0; k < DMODEL; ++k) {
        float w0 = Wfc[(size_t)k * DMODEL + j0];
        float w1 = Wfc[(size_t)k * DMODEL + j1];
        float4 xa = *(const float4*)&xs[k][0];
        float4 xb = *(const float4*)&xs[k][4];
        acc0[0] += xa.x * w0; acc0[1] += xa.y * w0; acc0[2] += xa.z * w0; acc0[3] += xa.w * w0;
        acc0[4] += xb.x * w0; acc0[5] += xb.y * w0; acc0[6] += xb.z * w0; acc0[7] += xb.w * w0;
        acc1[0] += xa.x * w1; acc1[1] += xa.y * w1; acc1[2] += xa.z * w1; acc1[3] += xa.w * w1;
        acc1[4] += xb.x * w1; acc1[5] += xb.y * w1; acc1[6] += xb.z * w1; acc1[7] += xb.w * w1;
    }

#pragma unroll
    for (int r = 0; r < 8; ++r) {
        os[r][j0] = acc0[r] + resid[(size_t)(m0 + r) * DMODEL + j0];
        os[r][j1] = acc1[r] + resid[(size_t)(m0 + r) * DMODEL + j1];
    }
    __syncthreads();

    const int wv = tid >> 6, ln = tid & 63;
#pragma unroll
    for (int rr = wv * 2; rr < wv * 2 + 2; ++rr) {
        float4 va = *(const float4*)&os[rr][ln * 8];
        float4 vb = *(const float4*)&os[rr][ln * 8 + 4];
        float sum = va.x + va.y + va.z + va.w + vb.x + vb.y + vb.z + vb.w;
        float sq = va.x * va.x + va.y * va.y + va.z * va.z + va.w * va.w
                 + vb.x * vb.x + vb.y * vb.y + vb.z * vb.z + vb.w * vb.w;
#pragma unroll
        for (int off = 32; off >= 1; off >>= 1) {
            sum += __shfl_xor(sum, off);
            sq += __shfl_xor(sq, off);
        }
        float mean = sum * (1.f / 512.f);
        float var = sq * (1.f / 512.f) - mean * mean;
        float rstd = rsqrtf(var + 1e-6f);

        float4 ga = *(const float4*)(gamma + ln * 8);
        float4 gb = *(const float4*)(gamma + ln * 8 + 4);
        float4 ba = *(const float4*)(beta + ln * 8);
        float4 bb = *(const float4*)(beta + ln * 8 + 4);

        float4 oa, ob;
        oa.x = (va.x - mean) * rstd * ga.x + ba.x;
        oa.y = (va.y - mean) * rstd * ga.y + ba.y;
        oa.z = (va.z - mean) * rstd * ga.z + ba.z;
        oa.w = (va.w - mean) * rstd * ga.w + ba.w;
        ob.x = (vb.x - mean) * rstd * gb.x + bb.x;
        ob.y = (vb.y - mean) * rstd * gb.y + bb.y;
        ob.z = (vb.z - mean) * rstd * gb.z + bb.z;
        ob.w = (vb.w - mean) * rstd * gb.w + bb.w;

        *(float4*)(out + (size_t)(m0 + rr) * DMODEL + ln * 8) = oa;
        *(float4*)(out + (size_t)(m0 + rr) * DMODEL + ln * 8 + 4) = ob;
    }
}

extern "C" void kernel_launch(void* const* d_in, const int* in_sizes, int n_in,
                              void* d_out, int out_size, void* d_ws, size_t ws_size,
                              hipStream_t stream)
{
    (void)in_sizes; (void)n_in; (void)out_size; (void)ws_size;

    const float* q   = (const float*)d_in[0];
    const float* k   = (const float*)d_in[1];
    const float* v   = (const float*)d_in[2];
    const float* Wq  = (const float*)d_in[3];
    const float* Wk  = (const float*)d_in[4];
    const float* Wv  = (const float*)d_in[5];
    const float* Wfc = (const float*)d_in[6];
    const float* g   = (const float*)d_in[7];
    const float* b   = (const float*)d_in[8];
    float* out = (float*)d_out;

    const size_t per = (size_t)BATCH * NSEQ * DMODEL;   // 4,194,304 elements
    ushort* qhb = (ushort*)d_ws;
    ushort* khb = qhb + per;
    float*  vh  = (float*)(khb + per);    // byte offset 16 MB, aligned
    float*  ao  = vh + per;

    dim3 pgrid(DMODEL / 64, (BATCH * NSEQ) / 64, 3);
    proj_kernel<<<pgrid, 256, 0, stream>>>(q, k, v, Wq, Wk, Wv, qhb, khb, vh);

    dim3 agrid(NSEQ / 16, BATCH * NHEAD);               // 128 x 32
    attn_kernel<<<agrid, 512, 0, stream>>>(qhb, khb, vh, ao);

    fc_ln_kernel<<<(BATCH * NSEQ) / 8, 256, 0, stream>>>(ao, Wfc, q, g, b, out);
}

// Round 3
// 525.054 us; speedup vs baseline: 3.7661x; 1.1740x over previous
//
#include <hip/hip_runtime.h>
#include <hip/hip_fp16.h>

#define BATCH 4
#define NSEQ 2048
#define DMODEL 512
#define NHEAD 8
#define HDIM 64
#define LSEL 32
#define SROWU 2056    // u16 elements per score row (2048 + 8 pad -> 16B-aligned rows)
#define MAXL 128      // selected-key list capacity (>=32 + tie headroom)

typedef __attribute__((ext_vector_type(8))) _Float16 f16x8;
typedef __attribute__((ext_vector_type(4))) float f32x4;

__device__ inline ushort f2h(float x) {
    __half h = __float2half(x);
    return *reinterpret_cast<ushort*>(&h);
}

// fp16 bits -> order-preserving u16 key
__device__ inline int h2sort(ushort h) {
    return (h & 0x8000u) ? (int)(h ^ 0xFFFFu) : (int)(h | 0x8000u);
}
// sortable u16 -> float value
__device__ inline float sort2f(int su) {
    ushort hb = (su & 0x8000) ? (ushort)(su ^ 0x8000) : (ushort)(su ^ 0xFFFF);
    __half th;
    *reinterpret_cast<ushort*>(&th) = hb;
    return __half2float(th);
}

// sum of per-lane counts c (0..32) across the wave, via 6 ballots
__device__ inline int wave_sum6(int c) {
    int tot = (int)__popcll(__ballot(c & 1));
    tot += (int)__popcll(__ballot(c & 2)) << 1;
    tot += (int)__popcll(__ballot(c & 4)) << 2;
    tot += (int)__popcll(__ballot(c & 8)) << 3;
    tot += (int)__popcll(__ballot(c & 16)) << 4;
    tot += (int)__popcll(__ballot(c & 32)) << 5;
    return tot;
}

// ---------------------------------------------------------------------------
// proj: C = A[M,512] @ W[512,512].  z=0(Q),1(K): fp16 out [B,H,N,64];
// z=2(V): fp32 out.  64x64 tile, BK=16, 256 thr, 4x4 micro-tile.
// ---------------------------------------------------------------------------
__global__ __launch_bounds__(256) void proj_kernel(
    const float* __restrict__ qin, const float* __restrict__ kin, const float* __restrict__ vin,
    const float* __restrict__ Wq, const float* __restrict__ Wk, const float* __restrict__ Wv,
    ushort* __restrict__ qhb, ushort* __restrict__ khb, float* __restrict__ vh)
{
    const int z = blockIdx.z;
    const float* A = (z == 0) ? qin : (z == 1) ? kin : vin;
    const float* W = (z == 0) ? Wq : (z == 1) ? Wk : Wv;

    __shared__ __align__(16) float As[16][68];
    __shared__ __align__(16) float Bs[16][68];

    const int tid = threadIdx.x;
    const int tx = tid & 15;
    const int ty = tid >> 4;
    const int bm = blockIdx.y * 64;
    const int bn = blockIdx.x * 64;

    const int sa_m = tid >> 2;
    const int sa_kq = (tid & 3) * 4;
    const int sb_k = tid >> 4;
    const int sb_n = (tid & 15) * 4;

    float acc[4][4] = {};

    for (int k0 = 0; k0 < DMODEL; k0 += 16) {
        __syncthreads();
        {
            float4 a4 = *(const float4*)(A + (size_t)(bm + sa_m) * DMODEL + k0 + sa_kq);
            As[sa_kq + 0][sa_m] = a4.x;
            As[sa_kq + 1][sa_m] = a4.y;
            As[sa_kq + 2][sa_m] = a4.z;
            As[sa_kq + 3][sa_m] = a4.w;
        }
        {
            float4 b4 = *(const float4*)(W + (size_t)(k0 + sb_k) * DMODEL + bn + sb_n);
            *(float4*)&Bs[sb_k][sb_n] = b4;
        }
        __syncthreads();
#pragma unroll
        for (int kk = 0; kk < 16; ++kk) {
            float4 a4 = *(const float4*)&As[kk][ty * 4];
            float4 b4 = *(const float4*)&Bs[kk][tx * 4];
            float av[4] = {a4.x, a4.y, a4.z, a4.w};
            float bv[4] = {b4.x, b4.y, b4.z, b4.w};
#pragma unroll
            for (int i = 0; i < 4; ++i)
#pragma unroll
                for (int j = 0; j < 4; ++j)
                    acc[i][j] += av[i] * bv[j];
        }
    }

    const int h = bn >> 6;
#pragma unroll
    for (int i = 0; i < 4; ++i) {
        int mg = bm + ty * 4 + i;
        int b = mg >> 11;
        int n = mg & (NSEQ - 1);
        size_t off = ((size_t)(b * NHEAD + h) * NSEQ + n) * HDIM + tx * 4;
        if (z == 2) {
            float4 o = {acc[i][0], acc[i][1], acc[i][2], acc[i][3]};
            *(float4*)(vh + off) = o;
        } else {
            ushort4 o = {f2h(acc[i][0]), f2h(acc[i][1]), f2h(acc[i][2]), f2h(acc[i][3])};
            if (z == 0) *(ushort4*)(qhb + off) = o;
            else        *(ushort4*)(khb + off) = o;
        }
    }
}

// ---------------------------------------------------------------------------
// attn v3: per block = (b,h) x 16 q-rows, 8 waves.
// Phase 1: QK^T via mfma_16x16x32_f16 (A=K tile, B=Q -> D[key][qrow]);
//          scores *0.125 -> fp16 -> sortable u16 -> LDS S[16][2056].
// Phase 2 (per q-row, 2 per wave): 32 keys/lane coalesced load;
//   (a) per-lane branchless top-4; (b) 16-iter ballot binary search for the
//       32nd largest of the 256-sample (3 ballots/iter, no LDS);
//   (c) one full verify pass (6-bit ballot sums of >= and >); exact refine
//       (full ballot search) iff count(>that) >= 32 [rare];
//   (d) ballot-bit prefix compaction -> (idx, w) list; sparse PV over fp32 V.
// ---------------------------------------------------------------------------
__global__ __launch_bounds__(512, 4) void attn_kernel(
    const ushort* __restrict__ qh, const ushort* __restrict__ kh,
    const float* __restrict__ vh, float* __restrict__ ao)
{
    __shared__ __align__(16) ushort Sbuf[16 * SROWU];   // 65792 B
    __shared__ ushort lidx[16][MAXL];
    __shared__ float  lw[16][MAXL];

    const int tid  = threadIdx.x;
    const int wave = tid >> 6;
    const int lane = tid & 63;
    const int bh   = blockIdx.y;
    const int q0   = blockIdx.x * 16;
    const int lr   = lane & 15;
    const int lg   = lane >> 4;

    const ushort* Qb = qh + ((size_t)bh * NSEQ + q0) * HDIM;
    const ushort* Kb = kh + (size_t)bh * NSEQ * HDIM;

    f16x8 qf0 = *(const f16x8*)(Qb + lr * HDIM + lg * 8);
    f16x8 qf1 = *(const f16x8*)(Qb + lr * HDIM + 32 + lg * 8);

    // -------- Phase 1: scores --------
    for (int t = 0; t < 16; ++t) {
        const int k0 = wave * 256 + t * 16;
        const ushort* Kt = Kb + (size_t)k0 * HDIM;
        f16x8 a0 = *(const f16x8*)(Kt + lr * HDIM + lg * 8);
        f16x8 a1 = *(const f16x8*)(Kt + lr * HDIM + 32 + lg * 8);
        f32x4 acc = {0.f, 0.f, 0.f, 0.f};
        acc = __builtin_amdgcn_mfma_f32_16x16x32_f16(a0, qf0, acc, 0, 0, 0);
        acc = __builtin_amdgcn_mfma_f32_16x16x32_f16(a1, qf1, acc, 0, 0, 0);
        // D: col=lane&15 = q-row, row=(lane>>4)*4+reg = key offset
        uint2 pk;
        pk.x = (unsigned)h2sort(f2h(acc[0] * 0.125f)) | ((unsigned)h2sort(f2h(acc[1] * 0.125f)) << 16);
        pk.y = (unsigned)h2sort(f2h(acc[2] * 0.125f)) | ((unsigned)h2sort(f2h(acc[3] * 0.125f)) << 16);
        *(uint2*)&Sbuf[lr * SROWU + k0 + lg * 4] = pk;
    }
    __syncthreads();

    // -------- Phase 2 --------
    const float* Vb = vh + (size_t)bh * NSEQ * HDIM;
    const int b = bh >> 3, hh = bh & 7;
    const unsigned long long below = (1ULL << lane) - 1ULL;

    for (int rr = 0; rr < 2; ++rr) {
        const int qr = wave * 2 + rr;
        const char* Srow = reinterpret_cast<const char*>(&Sbuf[qr * SROWU]);

        // 32 sortable keys per lane; key index = (j>>3)*512 + lane*8 + (j&7)
        int u[32];
#pragma unroll
        for (int it = 0; it < 4; ++it) {
            uint4 raw = *reinterpret_cast<const uint4*>(Srow + it * 1024 + lane * 16);
            u[it * 8 + 0] = (int)(raw.x & 0xFFFFu); u[it * 8 + 1] = (int)(raw.x >> 16);
            u[it * 8 + 2] = (int)(raw.y & 0xFFFFu); u[it * 8 + 3] = (int)(raw.y >> 16);
            u[it * 8 + 4] = (int)(raw.z & 0xFFFFu); u[it * 8 + 5] = (int)(raw.z >> 16);
            u[it * 8 + 6] = (int)(raw.w & 0xFFFFu); u[it * 8 + 7] = (int)(raw.w >> 16);
        }

        // (a) per-lane top-4 (sorted t0>=t1>=t2>=t3), branchless
        int t0 = 0, t1 = 0, t2 = 0, t3 = 0;
#pragma unroll
        for (int j = 0; j < 32; ++j) {
            int x = u[j];
            int a = min(x, t0); t0 = max(x, t0);
            int c = min(a, t1); t1 = max(a, t1);
            int d = min(c, t2); t2 = max(c, t2);
            t3 = max(d, t3);
        }

        // wave max (for exp shift)
        int mx = t0;
#pragma unroll
        for (int off = 32; off >= 1; off >>= 1) mx = max(mx, __shfl_xor(mx, off));
        const float Mv = sort2f(mx);

        // (b) 32nd largest of the 256-value sample (lower bound on true thr)
        int lo = 0, hi = 0xFFFF;
#pragma unroll
        for (int it = 0; it < 16; ++it) {
            int mid = (lo + hi + 1) >> 1;
            int c = (t0 >= mid) + (t1 >= mid) + (t2 >= mid) + (t3 >= mid);
            int tot = (int)__popcll(__ballot(c & 1))
                    + ((int)__popcll(__ballot(c & 2)) << 1)
                    + ((int)__popcll(__ballot(c & 4)) << 2);
            bool ge = tot >= LSEL;
            lo = ge ? mid : lo;
            hi = ge ? hi : mid - 1;
        }
        const int that = lo;

        // (c) verify against full row
        int cgt_l = 0;
#pragma unroll
        for (int j = 0; j < 32; ++j) cgt_l += (u[j] > that) ? 1 : 0;
        const int cgt = wave_sum6(cgt_l);

        int thr = that;
        if (cgt >= LSEL) {               // wave-uniform, rare: sample missed
            int flo = that, fhi = 0xFFFF;
#pragma unroll 1
            for (int it = 0; it < 16; ++it) {
                int mid = (flo + fhi + 1) >> 1;
                int cl = 0;
#pragma unroll
                for (int j = 0; j < 32; ++j) cl += (u[j] >= mid) ? 1 : 0;
                bool ge = wave_sum6(cl) >= LSEL;
                flo = ge ? mid : flo;
                fhi = ge ? fhi : mid - 1;
            }
            thr = flo;
        }

        // (d) selected count + exclusive lane prefix via ballot bits
        int csel = 0;
#pragma unroll
        for (int j = 0; j < 32; ++j) csel += (u[j] >= thr) ? 1 : 0;
        int pre = 0, totsel = 0;
#pragma unroll
        for (int bb = 0; bb < 6; ++bb) {
            unsigned long long m = __ballot((csel >> bb) & 1);
            pre += (int)__popcll(m & below) << bb;
            totsel += (int)__popcll(m) << bb;
        }

        // extraction: lane-major deterministic order
        float wpart = 0.f;
        int pos = pre;
#pragma unroll
        for (int j = 0; j < 32; ++j) {
            if (u[j] >= thr) {
                float s = sort2f(u[j]);
                float w = exp2f((s - Mv) * 1.4426950408889634f);
                if (pos < MAXL) {
                    lidx[qr][pos] = (ushort)((j >> 3) * 512 + lane * 8 + (j & 7));
                    lw[qr][pos] = w;
                    wpart += w;
                }
                ++pos;
            }
        }
#pragma unroll
        for (int off = 32; off >= 1; off >>= 1) wpart += __shfl_xor(wpart, off);
        const float wsum = wpart;
        const int nk = (totsel < MAXL) ? totsel : MAXL;

        // sparse PV: lane = output dim; coalesced 256B row gathers (L2-hot)
        float o = 0.f;
        int j2 = 0;
        for (; j2 + 4 <= nk; j2 += 4) {
            int i0 = lidx[qr][j2 + 0]; float w0 = lw[qr][j2 + 0];
            int i1 = lidx[qr][j2 + 1]; float w1 = lw[qr][j2 + 1];
            int i2 = lidx[qr][j2 + 2]; float w2 = lw[qr][j2 + 2];
            int i3 = lidx[qr][j2 + 3]; float w3 = lw[qr][j2 + 3];
            float v0 = Vb[(size_t)i0 * HDIM + lane];
            float v1 = Vb[(size_t)i1 * HDIM + lane];
            float v2 = Vb[(size_t)i2 * HDIM + lane];
            float v3 = Vb[(size_t)i3 * HDIM + lane];
            o += w0 * v0; o += w1 * v1; o += w2 * v2; o += w3 * v3;
        }
        for (; j2 < nk; ++j2) {
            int i0 = lidx[qr][j2]; float w0 = lw[qr][j2];
            o += w0 * Vb[(size_t)i0 * HDIM + lane];
        }

        ao[((size_t)(b * NSEQ) + q0 + qr) * DMODEL + hh * HDIM + lane] = o / wsum;
    }
}

// ---------------------------------------------------------------------------
// fc + residual + LayerNorm: 8 rows/block, 256 threads; x transposed in LDS.
// ---------------------------------------------------------------------------
__global__ __launch_bounds__(256) void fc_ln_kernel(
    const float* __restrict__ ao, const float* __restrict__ Wfc,
    const float* __restrict__ resid, const float* __restrict__ gamma,
    const float* __restrict__ beta, float* __restrict__ out)
{
    __shared__ __align__(16) float xs[DMODEL][12];
    __shared__ __align__(16) float os[8][DMODEL + 4];

    const int tid = threadIdx.x;
    const int m0 = blockIdx.x * 8;

#pragma unroll
    for (int it = 0; it < 4; ++it) {
        int f = tid + 256 * it;
        int r = f & 7;
        int kq = (f >> 3) * 4;
        float4 x4 = *(const float4*)(ao + (size_t)(m0 + r) * DMODEL + kq);
        xs[kq + 0][r] = x4.x;
        xs[kq + 1][r] = x4.y;
        xs[kq + 2][r] = x4.z;
        xs[kq + 3][r] = x4.w;
    }
    __syncthreads();

    const int j0 = tid;
    const int j1 = tid + 256;
    float acc0[8] = {}, acc1[8] = {};
#pragma unroll 4
    for (int k = 0; k < DMODEL; ++k) {
        float w0 = Wfc[(size_t)k * DMODEL + j0];
        float w1 = Wfc[(size_t)k * DMODEL + j1];
        float4 xa = *(const float4*)&xs[k][0];
        float4 xb = *(const float4*)&xs[k][4];
        acc0[0] += xa.x * w0; acc0[1] += xa.y * w0; acc0[2] += xa.z * w0; acc0[3] += xa.w * w0;
        acc0[4] += xb.x * w0; acc0[5] += xb.y * w0; acc0[6] += xb.z * w0; acc0[7] += xb.w * w0;
        acc1[0] += xa.x * w1; acc1[1] += xa.y * w1; acc1[2] += xa.z * w1; acc1[3] += xa.w * w1;
        acc1[4] += xb.x * w1; acc1[5] += xb.y * w1; acc1[6] += xb.z * w1; acc1[7] += xb.w * w1;
    }

#pragma unroll
    for (int r = 0; r < 8; ++r) {
        os[r][j0] = acc0[r] + resid[(size_t)(m0 + r) * DMODEL + j0];
        os[r][j1] = acc1[r] + resid[(size_t)(m0 + r) * DMODEL + j1];
    }
    __syncthreads();

    const int wv = tid >> 6, ln = tid & 63;
#pragma unroll
    for (int rr = wv * 2; rr < wv * 2 + 2; ++rr) {
        float4 va = *(const float4*)&os[rr][ln * 8];
        float4 vb = *(const float4*)&os[rr][ln * 8 + 4];
        float sum = va.x + va.y + va.z + va.w + vb.x + vb.y + vb.z + vb.w;
        float sq = va.x * va.x + va.y * va.y + va.z * va.z + va.w * va.w
                 + vb.x * vb.x + vb.y * vb.y + vb.z * vb.z + vb.w * vb.w;
#pragma unroll
        for (int off = 32; off >= 1; off >>= 1) {
            sum += __shfl_xor(sum, off);
            sq += __shfl_xor(sq, off);
        }
        float mean = sum * (1.f / 512.f);
        float var = sq * (1.f / 512.f) - mean * mean;
        float rstd = rsqrtf(var + 1e-6f);

        float4 ga = *(const float4*)(gamma + ln * 8);
        float4 gb = *(const float4*)(gamma + ln * 8 + 4);
        float4 ba = *(const float4*)(beta + ln * 8);
        float4 bb = *(const float4*)(beta + ln * 8 + 4);

        float4 oa, ob;
        oa.x = (va.x - mean) * rstd * ga.x + ba.x;
        oa.y = (va.y - mean) * rstd * ga.y + ba.y;
        oa.z = (va.z - mean) * rstd * ga.z + ba.z;
        oa.w = (va.w - mean) * rstd * ga.w + ba.w;
        ob.x = (vb.x - mean) * rstd * gb.x + bb.x;
        ob.y = (vb.y - mean) * rstd * gb.y + bb.y;
        ob.z = (vb.z - mean) * rstd * gb.z + bb.z;
        ob.w = (vb.w - mean) * rstd * gb.w + bb.w;

        *(float4*)(out + (size_t)(m0 + rr) * DMODEL + ln * 8) = oa;
        *(float4*)(out + (size_t)(m0 + rr) * DMODEL + ln * 8 + 4) = ob;
    }
}

extern "C" void kernel_launch(void* const* d_in, const int* in_sizes, int n_in,
                              void* d_out, int out_size, void* d_ws, size_t ws_size,
                              hipStream_t stream)
{
    (void)in_sizes; (void)n_in; (void)out_size; (void)ws_size;

    const float* q   = (const float*)d_in[0];
    const float* k   = (const float*)d_in[1];
    const float* v   = (const float*)d_in[2];
    const float* Wq  = (const float*)d_in[3];
    const float* Wk  = (const float*)d_in[4];
    const float* Wv  = (const float*)d_in[5];
    const float* Wfc = (const float*)d_in[6];
    const float* g   = (const float*)d_in[7];
    const float* b   = (const float*)d_in[8];
    float* out = (float*)d_out;

    const size_t per = (size_t)BATCH * NSEQ * DMODEL;   // 4,194,304 elements
    ushort* qhb = (ushort*)d_ws;
    ushort* khb = qhb + per;
    float*  vh  = (float*)(khb + per);
    float*  ao  = vh + per;

    dim3 pgrid(DMODEL / 64, (BATCH * NSEQ) / 64, 3);
    proj_kernel<<<pgrid, 256, 0, stream>>>(q, k, v, Wq, Wk, Wv, qhb, khb, vh);

    dim3 agrid(NSEQ / 16, BATCH * NHEAD);               // 128 x 32
    attn_kernel<<<agrid, 512, 0, stream>>>(qhb, khb, vh, ao);

    fc_ln_kernel<<<(BATCH * NSEQ) / 8, 256, 0, stream>>>(ao, Wfc, q, g, b, out);
}

// Round 4
// 317.979 us; speedup vs baseline: 6.2187x; 1.6512x over previous
//
#include <hip/hip_runtime.h>
#include <hip/hip_fp16.h>

#define BATCH 4
#define NSEQ 2048
#define DMODEL 512
#define NHEAD 8
#define HDIM 64
#define LSEL 32
#define SROWU 2056    // u16 elements per score row (2048 + 8 pad)
#define MAXL 128

typedef __attribute__((ext_vector_type(8))) _Float16 f16x8;
typedef __attribute__((ext_vector_type(4))) float f32x4;

__device__ inline ushort f2h(float x) { __half h = __float2half(x); return *reinterpret_cast<ushort*>(&h); }
__device__ inline uint h2sort(ushort h) { return (h & 0x8000u) ? (uint)(h ^ 0xFFFFu) : (uint)(h | 0x8000u); }
__device__ inline float sort2f(uint su) {
    ushort hb = (su & 0x8000u) ? (ushort)(su ^ 0x8000u) : (ushort)(su ^ 0xFFFFu);
    __half th; *reinterpret_cast<ushort*>(&th) = hb;
    return __half2float(th);
}

// ---------------------------------------------------------------------------
// cvtA: fp32 -> fp16 copies of q,k,v
// ---------------------------------------------------------------------------
__global__ __launch_bounds__(256) void cvtA_kernel(
    const float* __restrict__ q, const float* __restrict__ k, const float* __restrict__ v,
    ushort* __restrict__ q16, ushort* __restrict__ k16, ushort* __restrict__ v16)
{
    const int z = blockIdx.y;
    const float* src = (z == 0) ? q : (z == 1) ? k : v;
    ushort* dst = (z == 0) ? q16 : (z == 1) ? k16 : v16;
    const size_t base = (size_t)blockIdx.x * 2048 + threadIdx.x * 4;
    float4 fa = *(const float4*)(src + base);
    float4 fb = *(const float4*)(src + base + 1024);
    ushort4 ha = {f2h(fa.x), f2h(fa.y), f2h(fa.z), f2h(fa.w)};
    ushort4 hb = {f2h(fb.x), f2h(fb.y), f2h(fb.z), f2h(fb.w)};
    *(ushort4*)(dst + base) = ha;
    *(ushort4*)(dst + base + 1024) = hb;
}

// ---------------------------------------------------------------------------
// cvtW: W[512][512] fp32 -> Wt[n][k] fp16 (transposed), 4 matrices
// ---------------------------------------------------------------------------
__global__ __launch_bounds__(256) void cvtW_kernel(
    const float* __restrict__ Wq, const float* __restrict__ Wk,
    const float* __restrict__ Wv, const float* __restrict__ Wfc,
    ushort* __restrict__ Wt)
{
    const int z = blockIdx.y;
    const float* W = (z == 0) ? Wq : (z == 1) ? Wk : (z == 2) ? Wv : Wfc;
    ushort* O = Wt + (size_t)z * DMODEL * DMODEL;
    const int gt = blockIdx.x * 256 + threadIdx.x;   // 0..16383
    const int n = gt & 511;
    const int kc = (gt >> 9) * 16;
    uint pk[8];
#pragma unroll
    for (int i = 0; i < 8; ++i) {
        uint lo = f2h(W[(size_t)(kc + 2 * i) * DMODEL + n]);
        uint hi = f2h(W[(size_t)(kc + 2 * i + 1) * DMODEL + n]);
        pk[i] = lo | (hi << 16);
    }
    uint4 u0 = {pk[0], pk[1], pk[2], pk[3]};
    uint4 u1 = {pk[4], pk[5], pk[6], pk[7]};
    *(uint4*)(O + (size_t)n * DMODEL + kc) = u0;
    *(uint4*)(O + (size_t)n * DMODEL + kc + 8) = u1;
}

// ---------------------------------------------------------------------------
// hgemm: OUT[8192,512] = A16[8192,512] @ W (Wt stored [n][k] fp16).
// BM=64, BN=512(full), BK=32; 4 waves, each 64x128; 16x16x32 f16 MFMA.
// MODE 0: head-split fp16 out [B,H,N,64] (z=0,1,2). MODE 1: fp32 row-major.
// ---------------------------------------------------------------------------
template<int MODE>
__global__ __launch_bounds__(256, 2) void hgemm_kernel(
    const ushort* __restrict__ A0, const ushort* __restrict__ A1, const ushort* __restrict__ A2,
    const ushort* __restrict__ Wt,
    ushort* __restrict__ O0, ushort* __restrict__ O1, ushort* __restrict__ O2,
    float* __restrict__ Ofc)
{
    __shared__ ushort Ah[64][40];
    __shared__ ushort Bh[512][40];   // also reused as epilogue staging

    const int tid = threadIdx.x;
    const int wave = tid >> 6, lane = tid & 63;
    const int lr = lane & 15, lg = lane >> 4;
    const int bm = blockIdx.x * 64;
    const int z = blockIdx.y;

    const ushort* A16 = (MODE == 0) ? (z == 0 ? A0 : z == 1 ? A1 : A2) : A0;
    const ushort* Wz = Wt + (size_t)((MODE == 0) ? z : 3) * (DMODEL * DMODEL);

    f32x4 acc[4][8];
#pragma unroll
    for (int i = 0; i < 4; ++i)
#pragma unroll
        for (int j = 0; j < 8; ++j) acc[i][j] = (f32x4){0.f, 0.f, 0.f, 0.f};

    const int sar = tid >> 2, sak = (tid & 3) * 8;

    for (int k0 = 0; k0 < DMODEL; k0 += 32) {
        __syncthreads();
        *(uint4*)&Ah[sar][sak] = *(const uint4*)(A16 + (size_t)(bm + sar) * DMODEL + k0 + sak);
#pragma unroll
        for (int i = 0; i < 8; ++i) {
            int n = sar + 64 * i;
            *(uint4*)&Bh[n][sak] = *(const uint4*)(Wz + (size_t)n * DMODEL + k0 + sak);
        }
        __syncthreads();
        f16x8 af[4];
#pragma unroll
        for (int fr = 0; fr < 4; ++fr) af[fr] = *(const f16x8*)&Ah[fr * 16 + lr][lg * 8];
#pragma unroll
        for (int fc2 = 0; fc2 < 8; ++fc2) {
            f16x8 bf = *(const f16x8*)&Bh[wave * 128 + fc2 * 16 + lr][lg * 8];
#pragma unroll
            for (int fr = 0; fr < 4; ++fr)
                acc[fr][fc2] = __builtin_amdgcn_mfma_f32_16x16x32_f16(af[fr], bf, acc[fr][fc2], 0, 0, 0);
        }
    }

    if (MODE == 1) {
#pragma unroll
        for (int fr = 0; fr < 4; ++fr)
#pragma unroll
            for (int fc2 = 0; fc2 < 8; ++fc2)
#pragma unroll
                for (int r = 0; r < 4; ++r)
                    Ofc[(size_t)(bm + fr * 16 + lg * 4 + r) * DMODEL + wave * 128 + fc2 * 16 + lr] = acc[fr][fc2][r];
        return;
    }

    // MODE 0 epilogue: LDS transpose -> coalesced head-split fp16 stores
    ushort* O = (z == 0) ? O0 : (z == 1) ? O1 : O2;
    const int b = bm >> 11;
    const int nseq0 = bm & (NSEQ - 1);
    ushort* smw = (ushort*)&Bh[0][0] + wave * (64 * 72);
#pragma unroll
    for (int hp = 0; hp < 2; ++hp) {
        __syncthreads();
#pragma unroll
        for (int f4 = 0; f4 < 4; ++f4) {
            int fc2 = hp * 4 + f4;
            int nl = f4 * 16 + lr;
#pragma unroll
            for (int fr = 0; fr < 4; ++fr)
#pragma unroll
                for (int r = 0; r < 4; ++r)
                    smw[(fr * 16 + lg * 4 + r) * 72 + nl] = f2h(acc[fr][fc2][r]);
        }
        __syncthreads();
        const int h = wave * 2 + hp;
        ushort* obase = O + ((size_t)(b * NHEAD + h) * NSEQ + nseq0) * HDIM;
#pragma unroll
        for (int i = 0; i < 8; ++i) {
            int m = i * 8 + (lane >> 3);
            int dc = (lane & 7) * 8;
            *(uint4*)(obase + (size_t)m * HDIM + dc) = *(const uint4*)(smw + m * 72 + dc);
        }
    }
}

// ---------------------------------------------------------------------------
// attention helpers
// ---------------------------------------------------------------------------
__device__ inline int wave_sum6(int c) {
    int tot = (int)__popcll(__ballot(c & 1));
    tot += (int)__popcll(__ballot(c & 2)) << 1;
    tot += (int)__popcll(__ballot(c & 4)) << 2;
    tot += (int)__popcll(__ballot(c & 8)) << 3;
    tot += (int)__popcll(__ballot(c & 16)) << 4;
    tot += (int)__popcll(__ballot(c & 32)) << 5;
    return tot;
}

__device__ uint full_thr(const ushort* Sr, int lane, uint lo0) {
    uint flo = lo0, fhi = 0xFFFFu;
    for (int it2 = 0; it2 < 16; ++it2) {
        uint mid = (flo + fhi + 1) >> 1, M = mid << 16;
        int cl = 0;
#pragma unroll
        for (int it = 0; it < 4; ++it) {
            uint4 r4 = *(const uint4*)(Sr + it * 512 + lane * 8);
            cl += ((r4.x << 16) >= M) + ((r4.x & 0xFFFF0000u) >= M);
            cl += ((r4.y << 16) >= M) + ((r4.y & 0xFFFF0000u) >= M);
            cl += ((r4.z << 16) >= M) + ((r4.z & 0xFFFF0000u) >= M);
            cl += ((r4.w << 16) >= M) + ((r4.w & 0xFFFF0000u) >= M);
        }
        bool ge = wave_sum6(cl) >= LSEL;
        flo = ge ? mid : flo;
        fhi = ge ? fhi : mid - 1;
    }
    return flo;
}

__device__ int recount(const ushort* Sr, int lane, uint th) {
    int cs = 0;
#pragma unroll
    for (int it = 0; it < 4; ++it) {
        uint4 r4 = *(const uint4*)(Sr + it * 512 + lane * 8);
        cs += ((r4.x << 16) >= th) + ((r4.x & 0xFFFF0000u) >= th);
        cs += ((r4.y << 16) >= th) + ((r4.y & 0xFFFF0000u) >= th);
        cs += ((r4.z << 16) >= th) + ((r4.z & 0xFFFF0000u) >= th);
        cs += ((r4.w << 16) >= th) + ((r4.w & 0xFFFF0000u) >= th);
    }
    return cs;
}

__device__ float extract_row(const ushort* Sr, int lane, uint th, float Mv,
                             int csel, int pre, ushort* li, float* lwp,
                             uint t0, uint t1, uint t2, uint t3)
{
    const float L2E = 1.4426950408889634f;
    float wp = 0.f;
    bool big = __any(csel > 4);
    if (!big) {
        uint tt0 = t0, tt1 = t1, tt2 = t2, tt3 = t3;
#pragma unroll
        for (int i = 0; i < 4; ++i) {
            uint t = (i == 0) ? tt0 : (i == 1) ? tt1 : (i == 2) ? tt2 : tt3;
            if (t >= th) {
                int pos = pre + i;
                float w = exp2f((sort2f(t >> 16) - Mv) * L2E);
                if (pos < MAXL) { li[pos] = (ushort)(t & 0xFFFFu); lwp[pos] = w; wp += w; }
            }
        }
    } else {
        int pos = pre;
#pragma unroll
        for (int it = 0; it < 4; ++it) {
            uint4 r4 = *(const uint4*)(Sr + it * 512 + lane * 8);
            uint ib = (uint)(it * 512 + lane * 8);
            uint wds[4] = {r4.x, r4.y, r4.z, r4.w};
#pragma unroll
            for (int c = 0; c < 4; ++c) {
                uint vL = wds[c] << 16, vH = wds[c] & 0xFFFF0000u;
                if (vL >= th) {
                    float w = exp2f((sort2f(vL >> 16) - Mv) * L2E);
                    if (pos < MAXL) { li[pos] = (ushort)(ib + c * 2); lwp[pos] = w; wp += w; }
                    ++pos;
                }
                if (vH >= th) {
                    float w = exp2f((sort2f(vH >> 16) - Mv) * L2E);
                    if (pos < MAXL) { li[pos] = (ushort)(ib + c * 2 + 1); lwp[pos] = w; wp += w; }
                    ++pos;
                }
            }
        }
    }
#pragma unroll
    for (int off = 32; off >= 1; off >>= 1) wp += __shfl_xor(wp, off);
    return wp;
}

#define INS(T0, T1, T2, T3, P) { uint m1_ = min(P, T0); T0 = max(P, T0); \
    uint m2_ = min(m1_, T1); T1 = max(m1_, T1); \
    uint m3_ = min(m2_, T2); T2 = max(m2_, T2); T3 = max(m3_, T3); }

// ---------------------------------------------------------------------------
// attn v4: phase 1 as v3 (fp16 MFMA QK^T -> sortable u16 LDS).
// phase 2: two rows per wave fully interleaved; packed (val<<16|idx) top-4;
// ballot binary search on sample; fused verify+csel; top-4 fast extraction.
// ---------------------------------------------------------------------------
__global__ __launch_bounds__(512, 4) void attn_kernel(
    const ushort* __restrict__ qh, const ushort* __restrict__ kh,
    const ushort* __restrict__ vh, ushort* __restrict__ ao)
{
    __shared__ __align__(16) ushort Sbuf[16 * SROWU];
    __shared__ ushort lidx[16][MAXL];
    __shared__ float  lw[16][MAXL];

    const int tid = threadIdx.x;
    const int wave = tid >> 6;
    const int lane = tid & 63;
    const int bh = blockIdx.y;
    const int q0 = blockIdx.x * 16;
    const int lr = lane & 15;
    const int lg = lane >> 4;

    const ushort* Qb = qh + ((size_t)bh * NSEQ + q0) * HDIM;
    const ushort* Kb = kh + (size_t)bh * NSEQ * HDIM;

    f16x8 qf0 = *(const f16x8*)(Qb + lr * HDIM + lg * 8);
    f16x8 qf1 = *(const f16x8*)(Qb + lr * HDIM + 32 + lg * 8);

    // -------- Phase 1: scores --------
    for (int t = 0; t < 16; ++t) {
        const int k0 = wave * 256 + t * 16;
        const ushort* Kt = Kb + (size_t)k0 * HDIM;
        f16x8 a0 = *(const f16x8*)(Kt + lr * HDIM + lg * 8);
        f16x8 a1 = *(const f16x8*)(Kt + lr * HDIM + 32 + lg * 8);
        f32x4 acc = {0.f, 0.f, 0.f, 0.f};
        acc = __builtin_amdgcn_mfma_f32_16x16x32_f16(a0, qf0, acc, 0, 0, 0);
        acc = __builtin_amdgcn_mfma_f32_16x16x32_f16(a1, qf1, acc, 0, 0, 0);
        uint2 pk;
        pk.x = h2sort(f2h(acc[0] * 0.125f)) | (h2sort(f2h(acc[1] * 0.125f)) << 16);
        pk.y = h2sort(f2h(acc[2] * 0.125f)) | (h2sort(f2h(acc[3] * 0.125f)) << 16);
        *(uint2*)&Sbuf[lr * SROWU + k0 + lg * 4] = pk;
    }
    __syncthreads();

    // -------- Phase 2: two rows per wave, interleaved --------
    const __half* Vb = (const __half*)vh + (size_t)bh * NSEQ * HDIM;
    const int b = bh >> 3, hh = bh & 7;
    const unsigned long long below = (1ULL << lane) - 1ULL;

    const int qrA = wave * 2, qrB = qrA + 1;
    const ushort* SrA = &Sbuf[qrA * SROWU];
    const ushort* SrB = &Sbuf[qrB * SROWU];

    // packed top-4 prepass
    uint tA0 = 0, tA1 = 0, tA2 = 0, tA3 = 0;
    uint tB0 = 0, tB1 = 0, tB2 = 0, tB3 = 0;
#pragma unroll
    for (int it = 0; it < 4; ++it) {
        uint4 a4 = *(const uint4*)(SrA + it * 512 + lane * 8);
        uint4 b4 = *(const uint4*)(SrB + it * 512 + lane * 8);
        uint ib = (uint)(it * 512 + lane * 8);
        uint p;
        p = (a4.x << 16) | (ib + 0); INS(tA0, tA1, tA2, tA3, p);
        p = (a4.x & 0xFFFF0000u) | (ib + 1); INS(tA0, tA1, tA2, tA3, p);
        p = (a4.y << 16) | (ib + 2); INS(tA0, tA1, tA2, tA3, p);
        p = (a4.y & 0xFFFF0000u) | (ib + 3); INS(tA0, tA1, tA2, tA3, p);
        p = (a4.z << 16) | (ib + 4); INS(tA0, tA1, tA2, tA3, p);
        p = (a4.z & 0xFFFF0000u) | (ib + 5); INS(tA0, tA1, tA2, tA3, p);
        p = (a4.w << 16) | (ib + 6); INS(tA0, tA1, tA2, tA3, p);
        p = (a4.w & 0xFFFF0000u) | (ib + 7); INS(tA0, tA1, tA2, tA3, p);
        p = (b4.x << 16) | (ib + 0); INS(tB0, tB1, tB2, tB3, p);
        p = (b4.x & 0xFFFF0000u) | (ib + 1); INS(tB0, tB1, tB2, tB3, p);
        p = (b4.y << 16) | (ib + 2); INS(tB0, tB1, tB2, tB3, p);
        p = (b4.y & 0xFFFF0000u) | (ib + 3); INS(tB0, tB1, tB2, tB3, p);
        p = (b4.z << 16) | (ib + 4); INS(tB0, tB1, tB2, tB3, p);
        p = (b4.z & 0xFFFF0000u) | (ib + 5); INS(tB0, tB1, tB2, tB3, p);
        p = (b4.w << 16) | (ib + 6); INS(tB0, tB1, tB2, tB3, p);
        p = (b4.w & 0xFFFF0000u) | (ib + 7); INS(tB0, tB1, tB2, tB3, p);
    }

    // wave max (exp shift)
    uint mxA = tA0, mxB = tB0;
#pragma unroll
    for (int off = 32; off >= 1; off >>= 1) {
        mxA = max(mxA, (uint)__shfl_xor((int)mxA, off));
        mxB = max(mxB, (uint)__shfl_xor((int)mxB, off));
    }
    const float MvA = sort2f(mxA >> 16), MvB = sort2f(mxB >> 16);

    // binary search for sample 32nd-largest (both rows interleaved)
    uint loA = 0, hiA = 0xFFFFu, loB = 0, hiB = 0xFFFFu;
#pragma unroll
    for (int it = 0; it < 16; ++it) {
        uint midA = (loA + hiA + 1) >> 1, MA = midA << 16;
        uint midB = (loB + hiB + 1) >> 1, MB = midB << 16;
        int cA = (tA0 >= MA) + (tA1 >= MA) + (tA2 >= MA) + (tA3 >= MA);
        int cB = (tB0 >= MB) + (tB1 >= MB) + (tB2 >= MB) + (tB3 >= MB);
        int totA = (int)__popcll(__ballot(cA & 1)) + ((int)__popcll(__ballot(cA & 2)) << 1)
                 + ((int)__popcll(__ballot(cA & 4)) << 2);
        int totB = (int)__popcll(__ballot(cB & 1)) + ((int)__popcll(__ballot(cB & 2)) << 1)
                 + ((int)__popcll(__ballot(cB & 4)) << 2);
        bool geA = totA >= LSEL, geB = totB >= LSEL;
        loA = geA ? midA : loA; hiA = geA ? hiA : midA - 1;
        loB = geB ? midB : loB; hiB = geB ? hiB : midB - 1;
    }

    // fused verify (count > thr) + csel (count >= thr)
    uint thA = loA << 16, thB = loB << 16;
    int cgtA = 0, cselA = 0, cgtB = 0, cselB = 0;
#pragma unroll
    for (int it = 0; it < 4; ++it) {
        uint4 a4 = *(const uint4*)(SrA + it * 512 + lane * 8);
        uint4 b4 = *(const uint4*)(SrB + it * 512 + lane * 8);
#define VC(w, th, cgt, csel) { uint vL_ = (w) << 16, vH_ = (w) & 0xFFFF0000u; \
        cgt += (vL_ > th) + (vH_ > th); csel += (vL_ >= th) + (vH_ >= th); }
        VC(a4.x, thA, cgtA, cselA) VC(a4.y, thA, cgtA, cselA)
        VC(a4.z, thA, cgtA, cselA) VC(a4.w, thA, cgtA, cselA)
        VC(b4.x, thB, cgtB, cselB) VC(b4.y, thB, cgtB, cselB)
        VC(b4.z, thB, cgtB, cselB) VC(b4.w, thB, cgtB, cselB)
#undef VC
    }
    const int CgtA = wave_sum6(cgtA);
    const int CgtB = wave_sum6(cgtB);

    if (CgtA >= LSEL) {  // rare, wave-uniform: sample missed the true 32nd
        thA = full_thr(SrA, lane, loA) << 16;
        cselA = recount(SrA, lane, thA);
    }
    if (CgtB >= LSEL) {
        thB = full_thr(SrB, lane, loB) << 16;
        cselB = recount(SrB, lane, thB);
    }

    // lane prefix + total of csel
    int preA = 0, totA2 = 0, preB = 0, totB2 = 0;
#pragma unroll
    for (int bb = 0; bb < 6; ++bb) {
        unsigned long long mA = __ballot((cselA >> bb) & 1);
        unsigned long long mB = __ballot((cselB >> bb) & 1);
        preA += (int)__popcll(mA & below) << bb; totA2 += (int)__popcll(mA) << bb;
        preB += (int)__popcll(mB & below) << bb; totB2 += (int)__popcll(mB) << bb;
    }

    float wsumA = extract_row(SrA, lane, thA, MvA, cselA, preA, &lidx[qrA][0], &lw[qrA][0], tA0, tA1, tA2, tA3);
    float wsumB = extract_row(SrB, lane, thB, MvB, cselB, preB, &lidx[qrB][0], &lw[qrB][0], tB0, tB1, tB2, tB3);

    asm volatile("s_waitcnt lgkmcnt(0)" ::: "memory");

    const int nkA = (totA2 < MAXL) ? totA2 : MAXL;
    const int nkB = (totB2 < MAXL) ? totB2 : MAXL;

    // sparse PV, lane = output dim
    float oA = 0.f, oB = 0.f;
    {
        int j = 0;
        for (; j + 4 <= nkA; j += 4) {
            int i0 = lidx[qrA][j + 0]; float w0 = lw[qrA][j + 0];
            int i1 = lidx[qrA][j + 1]; float w1 = lw[qrA][j + 1];
            int i2 = lidx[qrA][j + 2]; float w2 = lw[qrA][j + 2];
            int i3 = lidx[qrA][j + 3]; float w3 = lw[qrA][j + 3];
            oA += w0 * __half2float(Vb[(size_t)i0 * HDIM + lane]);
            oA += w1 * __half2float(Vb[(size_t)i1 * HDIM + lane]);
            oA += w2 * __half2float(Vb[(size_t)i2 * HDIM + lane]);
            oA += w3 * __half2float(Vb[(size_t)i3 * HDIM + lane]);
        }
        for (; j < nkA; ++j)
            oA += lw[qrA][j] * __half2float(Vb[(size_t)lidx[qrA][j] * HDIM + lane]);
    }
    {
        int j = 0;
        for (; j + 4 <= nkB; j += 4) {
            int i0 = lidx[qrB][j + 0]; float w0 = lw[qrB][j + 0];
            int i1 = lidx[qrB][j + 1]; float w1 = lw[qrB][j + 1];
            int i2 = lidx[qrB][j + 2]; float w2 = lw[qrB][j + 2];
            int i3 = lidx[qrB][j + 3]; float w3 = lw[qrB][j + 3];
            oB += w0 * __half2float(Vb[(size_t)i0 * HDIM + lane]);
            oB += w1 * __half2float(Vb[(size_t)i1 * HDIM + lane]);
            oB += w2 * __half2float(Vb[(size_t)i2 * HDIM + lane]);
            oB += w3 * __half2float(Vb[(size_t)i3 * HDIM + lane]);
        }
        for (; j < nkB; ++j)
            oB += lw[qrB][j] * __half2float(Vb[(size_t)lidx[qrB][j] * HDIM + lane]);
    }

    ao[((size_t)(b * NSEQ) + q0 + qrA) * DMODEL + hh * HDIM + lane] = f2h(oA / wsumA);
    ao[((size_t)(b * NSEQ) + q0 + qrB) * DMODEL + hh * HDIM + lane] = f2h(oB / wsumB);
}

// ---------------------------------------------------------------------------
// LN: out = LN(fc_raw + resid) * g + b ; 4 waves/block, 1 row/wave
// ---------------------------------------------------------------------------
__global__ __launch_bounds__(256) void ln_kernel(
    const float* __restrict__ fcr, const float* __restrict__ resid,
    const float* __restrict__ g, const float* __restrict__ bta, float* __restrict__ out)
{
    const int row = blockIdx.x * 4 + (threadIdx.x >> 6);
    const int lane = threadIdx.x & 63;
    const size_t base = (size_t)row * DMODEL + lane * 8;
    float4 xa = *(const float4*)(fcr + base);
    float4 xb = *(const float4*)(fcr + base + 4);
    float4 ra = *(const float4*)(resid + base);
    float4 rb = *(const float4*)(resid + base + 4);
    xa.x += ra.x; xa.y += ra.y; xa.z += ra.z; xa.w += ra.w;
    xb.x += rb.x; xb.y += rb.y; xb.z += rb.z; xb.w += rb.w;
    float sum = xa.x + xa.y + xa.z + xa.w + xb.x + xb.y + xb.z + xb.w;
    float sq = xa.x * xa.x + xa.y * xa.y + xa.z * xa.z + xa.w * xa.w
             + xb.x * xb.x + xb.y * xb.y + xb.z * xb.z + xb.w * xb.w;
#pragma unroll
    for (int off = 32; off >= 1; off >>= 1) {
        sum += __shfl_xor(sum, off);
        sq += __shfl_xor(sq, off);
    }
    float mean = sum * (1.f / 512.f);
    float var = sq * (1.f / 512.f) - mean * mean;
    float rstd = rsqrtf(var + 1e-6f);
    float4 ga = *(const float4*)(g + lane * 8);
    float4 gb = *(const float4*)(g + lane * 8 + 4);
    float4 ba = *(const float4*)(bta + lane * 8);
    float4 bb = *(const float4*)(bta + lane * 8 + 4);
    float4 oa, ob;
    oa.x = (xa.x - mean) * rstd * ga.x + ba.x;
    oa.y = (xa.y - mean) * rstd * ga.y + ba.y;
    oa.z = (xa.z - mean) * rstd * ga.z + ba.z;
    oa.w = (xa.w - mean) * rstd * ga.w + ba.w;
    ob.x = (xb.x - mean) * rstd * gb.x + bb.x;
    ob.y = (xb.y - mean) * rstd * gb.y + bb.y;
    ob.z = (xb.z - mean) * rstd * gb.z + bb.z;
    ob.w = (xb.w - mean) * rstd * gb.w + bb.w;
    *(float4*)(out + base) = oa;
    *(float4*)(out + base + 4) = ob;
}

extern "C" void kernel_launch(void* const* d_in, const int* in_sizes, int n_in,
                              void* d_out, int out_size, void* d_ws, size_t ws_size,
                              hipStream_t stream)
{
    (void)in_sizes; (void)n_in; (void)out_size; (void)ws_size;

    const float* q   = (const float*)d_in[0];
    const float* k   = (const float*)d_in[1];
    const float* v   = (const float*)d_in[2];
    const float* Wq  = (const float*)d_in[3];
    const float* Wk  = (const float*)d_in[4];
    const float* Wv  = (const float*)d_in[5];
    const float* Wfc = (const float*)d_in[6];
    const float* g   = (const float*)d_in[7];
    const float* b   = (const float*)d_in[8];
    float* out = (float*)d_out;

    const size_t SZ = (size_t)BATCH * NSEQ * DMODEL;      // 4,194,304
    const size_t WSZ = (size_t)DMODEL * DMODEL;           // 262,144
    ushort* w16 = (ushort*)d_ws;
    ushort* q16 = w16;
    ushort* k16 = w16 + SZ;
    ushort* v16 = w16 + 2 * SZ;
    ushort* Wt  = w16 + 3 * SZ;                           // 4 matrices
    ushort* qh  = Wt + 4 * WSZ;
    ushort* kh  = qh + SZ;
    ushort* vh  = kh + SZ;
    ushort* ao  = vh + SZ;
    float* fc_raw = (float*)d_ws;   // overlays q16+k16 (dead by fc time)

    cvtA_kernel<<<dim3(2048, 3), 256, 0, stream>>>(q, k, v, q16, k16, v16);
    cvtW_kernel<<<dim3(64, 4), 256, 0, stream>>>(Wq, Wk, Wv, Wfc, Wt);
    hgemm_kernel<0><<<dim3(128, 3), 256, 0, stream>>>(q16, k16, v16, Wt, qh, kh, vh, nullptr);
    attn_kernel<<<dim3(NSEQ / 16, BATCH * NHEAD), 512, 0, stream>>>(qh, kh, vh, ao);
    hgemm_kernel<1><<<dim3(128, 1), 256, 0, stream>>>(ao, nullptr, nullptr, Wt, nullptr, nullptr, nullptr, fc_raw);
    ln_kernel<<<(BATCH * NSEQ) / 4, 256, 0, stream>>>(fc_raw, q, g, b, out);
}